// Round 5
// baseline (179.331 us; speedup 1.0000x reference)
//
#include <hip/hip_runtime.h>
#include <math.h>

// Problem constants (fixed by setup_inputs)
constexpr int N_ = 8, C_ = 256, F_ = 16, WH_ = 784;
constexpr int CH_STRIDE = F_ * WH_;        // 12544 floats between channels
constexpr int COUT_SZ = N_ * F_ * WH_;     // 100352 floats (c output)
constexpr int TILE = 56;                   // positions per LDS tile
constexpr int NT = 7;                      // tiles per block (392 positions)
constexpr int LSTR = 60;                   // padded LDS row stride (floats):
                                           //   60*4=240 B keeps float4 16B-aligned;
                                           //   60%32=28 spreads banks (2-way max)
constexpr int F4PT = TILE / 4;             // 14 float4 per channel per tile
constexpr int STAGE_TOT = C_ * F4PT;       // 3584 float4 staged per tile

__device__ inline float wave_reduce_sum(float v) {
#pragma unroll
  for (int o = 32; o > 0; o >>= 1) v += __shfl_down(v, o, 64);
  return v;
}

// ---------------- Kernel 1: fused single-read (c + online S,G partials) ----
// grid 256 = (nf << 1 | ph). Block owns 392 positions x all 256 channels of
// l[n,:,f,:], streamed ONCE through a 61 KB LDS tile (R0/R2/R4 all pinned at
// ~46us because they read l twice; this halves traffic).
// Max-free online softmax (proven R2/R4): per tile accumulate
//   S += sum_p exp(c_p),  G_c += sum_p exp(c_p)*l[c,p]
// from the resident tile; g_out = G/S combined across the (nf,0)/(nf,1) pair
// by K2. Register-staged prefetch of tile t+1 overlaps HBM latency with the
// c-dot and G phases (single LDS buffer, <64KB static limit).
__global__ __launch_bounds__(1024) void fused_kernel(
    const float* __restrict__ l, const float* __restrict__ g,
    const float* __restrict__ w, float* __restrict__ out,
    float* __restrict__ ws) {
  __shared__ float buf[C_ * LSTR];  // 61440 B tile buffer
  __shared__ float w_s[C_];
  __shared__ float e_s[TILE];
  __shared__ float red_s[16];
  __shared__ float gb_s;

  const int bid = blockIdx.x;
  const int nf = bid >> 1, ph = bid & 1;
  const int n = nf >> 4, f = nf & 15;
  const int tid = threadIdx.x;
  const int lane = tid & 63, wv = tid >> 6;

  // ---- prologue: w into LDS, gb = sum_c g[n,c]*w[c] ----
  if (tid < C_) w_s[tid] = w[tid];
  float gv = (tid < C_) ? g[n * C_ + tid] * w[tid] : 0.f;
  gv = wave_reduce_sum(gv);
  if (lane == 0) red_s[wv] = gv;
  __syncthreads();  // also makes w_s visible
  if (tid == 0) {
    float s = 0.f;
#pragma unroll
    for (int i = 0; i < 16; ++i) s += red_s[i];
    gb_s = s;
  }
  __syncthreads();
  const float gb = gb_s;

  // ---- precompute per-thread stage mapping (constant across tiles) ----
  // float4 index within a tile: idx = c*14 + j, covered as idx = k*1024+tid,
  // k=0..2 for all threads, k=3 for tid<512 (3584 total).
  int offG[4], offL[4];
  bool act[4];
#pragma unroll
  for (int k = 0; k < 4; ++k) {
    const int idx = k * 1024 + tid;
    act[k] = (k < 3) || (tid < 512);
    const int c = act[k] ? (idx / F4PT) : 0;
    const int j = idx - c * F4PT;
    offG[k] = c * CH_STRIDE + (j << 2);  // floats into l, from tile base
    offL[k] = c * LSTR + (j << 2);       // floats into buf
  }
  // tile base (floats): l[n, c=0, f, ph*392 + t*56]
  const size_t gbase =
      (size_t)n * (C_ * CH_STRIDE) + (size_t)f * WH_ + ph * 392;

  float4 st[4];
  // stage tile 0
#pragma unroll
  for (int k = 0; k < 4; ++k)
    if (act[k]) st[k] = *reinterpret_cast<const float4*>(l + gbase + offG[k]);

  float gacc = 0.f;   // G partial for this thread's (channel, quarter)
  float s_part = 0.f; // S partial (only s==0 threads of c-phase contribute)
  const int gc = tid >> 2, q = tid & 3;  // G-phase mapping
  const int p = tid >> 3, s8 = tid & 7;  // c-phase mapping (tid<448 active)

  for (int t = 0; t < NT; ++t) {
    // write staged regs -> LDS (compiler inserts vmcnt before use)
#pragma unroll
    for (int k = 0; k < 4; ++k)
      if (act[k]) *reinterpret_cast<float4*>(&buf[offL[k]]) = st[k];
    __syncthreads();  // tile resident

    // issue next tile's global loads early: latency hides under c+G phases
    if (t + 1 < NT) {
      const float* lp = l + gbase + (t + 1) * TILE;
#pragma unroll
      for (int k = 0; k < 4; ++k)
        if (act[k]) st[k] = *reinterpret_cast<const float4*>(lp + offG[k]);
    }

    // ---- c-phase: c_p = sum_c l*w + gb; 8 lanes per position ----
    if (tid < TILE * 8) {
      float acc = 0.f;
#pragma unroll
      for (int k = 0; k < 32; ++k) {
        const int c = s8 + (k << 3);
        acc = fmaf(buf[c * LSTR + p], w_s[c], acc);
      }
      acc += __shfl_down(acc, 4, 64);
      acc += __shfl_down(acc, 2, 64);
      acc += __shfl_down(acc, 1, 64);
      if (s8 == 0) {
        const float cp = acc + gb;
        out[nf * WH_ + ph * 392 + t * TILE + p] = cp;
        const float e = __expf(cp);
        e_s[p] = e;
        s_part += e;
      }
    }
    __syncthreads();  // e_s ready

    // ---- G-phase: thread (gc,q) accumulates 14 positions of channel gc ----
    {
      const int pb = q * F4PT;  // NOTE: F4PT==14 == positions per quarter
#pragma unroll
      for (int j = 0; j < 14; ++j)
        gacc = fmaf(buf[gc * LSTR + pb + j], e_s[pb + j], gacc);
    }
    __syncthreads();  // all reads of buf/e_s done before next tile overwrite
  }

  // ---- epilogue: publish partials ----
  gacc += __shfl_down(gacc, 2, 64);
  gacc += __shfl_down(gacc, 1, 64);
  if (q == 0) ws[bid * C_ + gc] = gacc;  // G partial, 256 floats/block

  float sp = wave_reduce_sum(s_part);
  if (lane == 0) red_s[wv] = sp;  // red_s reuse: prologue long done
  __syncthreads();
  if (tid == 0) {
    float ssum = 0.f;
#pragma unroll
    for (int i = 0; i < 16; ++i) ssum += red_s[i];
    ws[65536 + bid] = ssum;  // S partial
  }
}

// ---------------- Kernel 2: combine pair partials -> g_out ----------------
// 32768 outputs = 32 blocks x 1024 threads; one (nf, c) each.
__global__ __launch_bounds__(1024) void combine_kernel(
    float* __restrict__ out, const float* __restrict__ ws) {
  const int tg = blockIdx.x * 1024 + threadIdx.x;
  const int nf = tg >> 8, c = tg & 255;
  const int n = nf >> 4, f = nf & 15;
  const float G = ws[(2 * nf) * C_ + c] + ws[(2 * nf + 1) * C_ + c];
  const float S = ws[65536 + 2 * nf] + ws[65536 + 2 * nf + 1];
  out[COUT_SZ + (size_t)(n * C_ + c) * F_ + f] = G / S;
}

extern "C" void kernel_launch(void* const* d_in, const int* in_sizes, int n_in,
                              void* d_out, int out_size, void* d_ws,
                              size_t ws_size, hipStream_t stream) {
  const float* l = (const float*)d_in[0];
  const float* g = (const float*)d_in[1];
  const float* w = (const float*)d_in[2];
  float* out = (float*)d_out;
  float* ws = (float*)d_ws;  // [0,65536): G partials; [65536,65792): S partials
  fused_kernel<<<dim3(2 * N_ * F_), dim3(1024), 0, stream>>>(l, g, w, out, ws);
  combine_kernel<<<dim3(32), dim3(1024), 0, stream>>>(out, ws);
}

// Round 6
// 160.627 us; speedup vs baseline: 1.1164x; 1.1164x over previous
//
#include <hip/hip_runtime.h>
#include <math.h>

// Problem constants (fixed by setup_inputs)
constexpr int N_ = 8, C_ = 256, F_ = 16, WH_ = 784;
constexpr int CH_STRIDE = F_ * WH_;        // 12544 floats between channels
constexpr int COUT_SZ = N_ * F_ * WH_;     // 100352 floats (c output)
constexpr int QP = 196;                    // positions per block (quarter row)
constexpr int TILE = 28;                   // positions per LDS tile
constexpr int NT = 7;                      // tiles per block
constexpr int LSTR = 36;                   // padded LDS row stride (floats):
                                           //   36%4==0 keeps float4 16B-aligned;
                                           //   bank step 4/channel -> ~2-way max
constexpr int F4PT = TILE / 4;             // 7 float4 per channel per tile
constexpr int SOFF = 512 * C_;             // ws offset of S partials

__device__ inline float wave_reduce_sum(float v) {
#pragma unroll
  for (int o = 32; o > 0; o >>= 1) v += __shfl_down(v, o, 64);
  return v;
}

// ---------------- Kernel 1: fused single-read (c + online S,G partials) ----
// grid 512 = (nf << 2 | qh): block owns 196 positions x all 256 channels,
// streamed ONCE through a 36 KB LDS tile. R5 lesson: register-held prefetch
// (st[4] across barriers) spilled to scratch (WRITE_SIZE 97MB == 6x64B x
// 262K threads) and grid==256 gave 1 block/CU (no TLP during staging).
// Here: straight-line synchronous staging (nothing held across barriers) +
// 2 blocks/CU (launch_bounds(1024,8), 38KB LDS) so a co-resident block's
// compute hides the other's HBM stage latency.
// Max-free online softmax (proven R2/R4/R5): per tile
//   S += sum_p exp(c_p), G_c += sum_p exp(c_p)*l[c,p]; g_out = G/S in K2.
__global__ __launch_bounds__(1024, 8) void fused_kernel(
    const float* __restrict__ l, const float* __restrict__ g,
    const float* __restrict__ w, float* __restrict__ out,
    float* __restrict__ ws) {
  __shared__ float buf[C_ * LSTR];  // 36864 B tile buffer
  __shared__ float w_s[C_];
  __shared__ float e_s[TILE];
  __shared__ float red_s[16];
  __shared__ float gb_s;

  const int bid = blockIdx.x;
  const int nf = bid >> 2, qh = bid & 3;
  const int n = nf >> 4, f = nf & 15;
  const int tid = threadIdx.x;
  const int lane = tid & 63, wv = tid >> 6;

  // ---- prologue: w into LDS, gb = sum_c g[n,c]*w[c] ----
  if (tid < C_) w_s[tid] = w[tid];
  float gv = (tid < C_) ? g[n * C_ + tid] * w[tid] : 0.f;
  gv = wave_reduce_sum(gv);
  if (lane == 0) red_s[wv] = gv;
  __syncthreads();  // also makes w_s visible
  if (tid == 0) {
    float s = 0.f;
#pragma unroll
    for (int i = 0; i < 16; ++i) s += red_s[i];
    gb_s = s;
  }
  __syncthreads();
  const float gb = gb_s;

  // ---- per-thread stage mapping (constant across tiles) ----
  // 1792 float4/tile = 256 ch x 7; slot0: all 1024 threads, slot1: tid<768.
  const int idx0 = tid;
  const int c0s = idx0 / F4PT, j0 = idx0 - c0s * F4PT;
  const int og0 = c0s * CH_STRIDE + (j0 << 2);
  const int ol0 = c0s * LSTR + (j0 << 2);
  const int idx1 = 1024 + tid;
  const int c1s = idx1 / F4PT, j1 = idx1 - c1s * F4PT;
  const int og1 = c1s * CH_STRIDE + (j1 << 2);
  const int ol1 = c1s * LSTR + (j1 << 2);
  const bool a1 = (tid < 768);
  const size_t gbase =
      (size_t)n * (C_ * CH_STRIDE) + (size_t)f * WH_ + qh * QP;

  // phase mappings
  const int p16 = tid >> 4, s16 = tid & 15;  // c-phase: 28 pos x 16 lanes
  const int gc = tid >> 2, q = tid & 3;      // G-phase: 256 ch x 4 quarters

  float gacc = 0.f;    // G partial: channel gc, positions q*7..q*7+6, all tiles
  float s_part = 0.f;  // S partial (s16==0 threads)

  for (int t = 0; t < NT; ++t) {
    // ---- stage tile t (synchronous; no regs live across barriers) ----
    {
      const float* lp = l + gbase + t * TILE;
      const float4 v0 = *reinterpret_cast<const float4*>(lp + og0);
      if (a1) {
        const float4 v1 = *reinterpret_cast<const float4*>(lp + og1);
        *reinterpret_cast<float4*>(&buf[ol1]) = v1;
      }
      *reinterpret_cast<float4*>(&buf[ol0]) = v0;
    }
    __syncthreads();  // tile resident

    // ---- c-phase: c_p = sum_c l*w + gb; 16 lanes per position ----
    if (tid < TILE * 16) {
      float acc = 0.f;
#pragma unroll
      for (int k = 0; k < 16; ++k) {
        const int c = s16 + (k << 4);
        acc = fmaf(buf[c * LSTR + p16], w_s[c], acc);
      }
      acc += __shfl_down(acc, 8, 64);
      acc += __shfl_down(acc, 4, 64);
      acc += __shfl_down(acc, 2, 64);
      acc += __shfl_down(acc, 1, 64);
      if (s16 == 0) {
        const float cp = acc + gb;
        out[nf * WH_ + qh * QP + t * TILE + p16] = cp;
        const float e = __expf(cp);
        e_s[p16] = e;
        s_part += e;
      }
    }
    __syncthreads();  // e_s ready

    // ---- G-phase: thread (gc,q) accumulates 7 positions of channel gc ----
    {
      const int pb = q * 7;
#pragma unroll
      for (int j = 0; j < 7; ++j)
        gacc = fmaf(buf[gc * LSTR + pb + j], e_s[pb + j], gacc);
    }
    __syncthreads();  // all buf/e_s reads done before next tile overwrite
  }

  // ---- epilogue: publish partials ----
  gacc += __shfl_down(gacc, 2, 64);
  gacc += __shfl_down(gacc, 1, 64);
  if (q == 0) ws[bid * C_ + gc] = gacc;  // 256 G partials per block

  float sp = wave_reduce_sum(s_part);
  if (lane == 0) red_s[wv] = sp;  // red_s reuse: prologue long done
  __syncthreads();
  if (tid == 0) {
    float ssum = 0.f;
#pragma unroll
    for (int i = 0; i < 16; ++i) ssum += red_s[i];
    ws[SOFF + bid] = ssum;  // S partial
  }
}

// ---------------- Kernel 2: combine quarter partials -> g_out -------------
// 32768 outputs = 32 blocks x 1024 threads; one (nf, c) each.
__global__ __launch_bounds__(1024) void combine_kernel(
    float* __restrict__ out, const float* __restrict__ ws) {
  const int tg = blockIdx.x * 1024 + threadIdx.x;
  const int nf = tg >> 8, c = tg & 255;
  const int n = nf >> 4, f = nf & 15;
  const int b0 = nf << 2;
  const float G = ws[(b0 + 0) * C_ + c] + ws[(b0 + 1) * C_ + c] +
                  ws[(b0 + 2) * C_ + c] + ws[(b0 + 3) * C_ + c];
  const float S = ws[SOFF + b0] + ws[SOFF + b0 + 1] +
                  ws[SOFF + b0 + 2] + ws[SOFF + b0 + 3];
  out[COUT_SZ + (size_t)(n * C_ + c) * F_ + f] = G / S;
}

extern "C" void kernel_launch(void* const* d_in, const int* in_sizes, int n_in,
                              void* d_out, int out_size, void* d_ws,
                              size_t ws_size, hipStream_t stream) {
  const float* l = (const float*)d_in[0];
  const float* g = (const float*)d_in[1];
  const float* w = (const float*)d_in[2];
  float* out = (float*)d_out;
  float* ws = (float*)d_ws;  // [0,131072): G partials; [131072,131584): S
  fused_kernel<<<dim3(4 * N_ * F_), dim3(1024), 0, stream>>>(l, g, w, out, ws);
  combine_kernel<<<dim3(32), dim3(1024), 0, stream>>>(out, ws);
}

// Round 7
// 159.591 us; speedup vs baseline: 1.1237x; 1.0065x over previous
//
#include <hip/hip_runtime.h>
#include <math.h>

// Problem constants (fixed by setup_inputs)
constexpr int N_ = 8, C_ = 256, F_ = 16, WH_ = 784;
constexpr int CH_STRIDE = F_ * WH_;        // 12544 floats between channels
constexpr int COUT_SZ = N_ * F_ * WH_;     // 100352 floats (c output)
constexpr int QP = 196;                    // positions per block (quarter row)
constexpr int TILE = 28;                   // positions per LDS tile
constexpr int NT = 7;                      // tiles per block
constexpr int F4PT = TILE / 4;             // 7 float4 per channel per tile
constexpr int TILE_F = C_ * TILE;          // 7168 floats per buffer (28 KB)
constexpr int SOFF = 512 * C_;             // ws offset of S partials

__device__ inline float wave_reduce_sum(float v) {
#pragma unroll
  for (int o = 32; o > 0; o >>= 1) v += __shfl_down(v, o, 64);
  return v;
}

// Async global->LDS, 16B per lane. LDS dest = wave-uniform base + lane*16
// (m104), so the LDS layout is linear float4 order; the per-lane GLOBAL
// address carries the gather pattern. Tracked by vmcnt; __syncthreads drains.
__device__ inline void gload16(const float* gp, float* lp) {
  __builtin_amdgcn_global_load_lds(
      (const __attribute__((address_space(1))) void*)gp,
      (__attribute__((address_space(3))) void*)lp, 16, 0, 0);
}

// ---------------- Kernel 1: fused single-read, 2-phase async pipeline ------
// grid 512 = (nf << 2 | qh): block owns 196 positions x 256 channels,
// streamed ONCE (R6 proved single-read; this round hides the stage latency).
// Per tile t: issue gload_lds of tile t+1 into the OTHER buffer (stays in
// flight), compute c-phase from cur, lgkm-only barrier (prefetch vmcnt NOT
// drained -- the m201-verified asm-barrier pattern), G-phase from cur, then
// one __syncthreads (full drain: prefetched tile now resident), swap.
// LDS layout: linear [c][28], stride 28 -> <=2-way bank conflicts (free).
// Max-free online softmax (proven R2-R6): S += sum exp(c), G_c += sum e*l.
__global__ __launch_bounds__(1024, 8) void fused_kernel(
    const float* __restrict__ l, const float* __restrict__ g,
    const float* __restrict__ w, float* __restrict__ out,
    float* __restrict__ ws) {
  __shared__ float bufA[TILE_F];
  __shared__ float bufB[TILE_F];
  __shared__ float w_s[C_];
  __shared__ float e_s[TILE];
  __shared__ float red_s[16];
  __shared__ float gb_s;

  const int bid = blockIdx.x;
  const int nf = bid >> 2, qh = bid & 3;
  const int n = nf >> 4, f = nf & 15;
  const int tid = threadIdx.x;
  const int lane = tid & 63, wv = tid >> 6;

  // ---- stage mapping: float4 idx within tile = c*7 + j ----
  // chunk wv covers idx wv*64+lane == tid; chunk 16+wv covers 1024+tid (wv<12)
  const int c0 = tid / F4PT, j0 = tid - c0 * F4PT;
  const int og0 = c0 * CH_STRIDE + (j0 << 2);
  const int idx1 = 1024 + tid;
  const int c1 = idx1 / F4PT, j1 = idx1 - c1 * F4PT;
  const int og1 = c1 * CH_STRIDE + (j1 << 2);
  const bool a1 = (tid < 768);          // wave-uniform (12 waves)
  const int l0 = wv << 8;               // uniform LDS float offset, chunk wv
  const int l1 = 4096 + (wv << 8);      // chunk 16+wv
  const size_t gbase =
      (size_t)n * (C_ * CH_STRIDE) + (size_t)f * WH_ + qh * QP;

  // issue tile 0 into bufA; its latency hides under the prologue
  {
    const float* lp = l + gbase;
    gload16(lp + og0, &bufA[l0]);
    if (a1) gload16(lp + og1, &bufA[l1]);
  }

  // ---- prologue: w into LDS, gb = sum_c g[n,c]*w[c] ----
  if (tid < C_) w_s[tid] = w[tid];
  float gv = (tid < C_) ? g[n * C_ + tid] * w[tid] : 0.f;
  gv = wave_reduce_sum(gv);
  if (lane == 0) red_s[wv] = gv;
  __syncthreads();  // drains vmcnt: tile 0 resident, w_s visible
  if (tid == 0) {
    float s = 0.f;
#pragma unroll
    for (int i = 0; i < 16; ++i) s += red_s[i];
    gb_s = s;
  }
  __syncthreads();
  const float gb = gb_s;

  // phase mappings
  const int p16 = tid >> 4, s16 = tid & 15;  // c-phase: 28 pos x 16 slices
  const int gc = tid >> 2, q = tid & 3;      // G-phase: 256 ch x 4 quarters

  float* cur = bufA;
  float* nxt = bufB;
  float gacc = 0.f;    // G partial: channel gc, positions q*7..q*7+6
  float s_part = 0.f;  // S partial (s16==0 threads)

  for (int t = 0; t < NT; ++t) {
    // issue tile t+1 into nxt: stays in flight across BOTH compute phases
    if (t + 1 < NT) {
      const float* lp = l + gbase + (t + 1) * TILE;
      gload16(lp + og0, &nxt[l0]);
      if (a1) gload16(lp + og1, &nxt[l1]);
    }

    // ---- c-phase: c_p = sum_c l*w + gb; 16 lanes per position ----
    if (tid < TILE * 16) {
      float acc = 0.f;
#pragma unroll
      for (int k = 0; k < 16; ++k) {
        const int c = s16 + (k << 4);
        acc = fmaf(cur[c * TILE + p16], w_s[c], acc);
      }
      acc += __shfl_down(acc, 8, 64);
      acc += __shfl_down(acc, 4, 64);
      acc += __shfl_down(acc, 2, 64);
      acc += __shfl_down(acc, 1, 64);
      if (s16 == 0) {
        const float cp = acc + gb;
        out[nf * WH_ + qh * QP + t * TILE + p16] = cp;
        const float e = __expf(cp);
        e_s[p16] = e;
        s_part += e;
      }
    }
    // e_s dependency is LDS-only: wait lgkm, NOT vmcnt (prefetch stays in
    // flight). m201-verified pattern; sched_barrier fences hoisting (#18).
    asm volatile("s_waitcnt lgkmcnt(0)" ::: "memory");
    __builtin_amdgcn_s_barrier();
    __builtin_amdgcn_sched_barrier(0);

    // ---- G-phase: thread (gc,q) accumulates 7 positions of channel gc ----
    {
      const int pb = q * 7;
#pragma unroll
      for (int j = 0; j < 7; ++j)
        gacc = fmaf(cur[gc * TILE + pb + j], e_s[pb + j], gacc);
    }
    __syncthreads();  // full drain: cur/e_s reads done AND tile t+1 resident

    float* tmp = cur; cur = nxt; nxt = tmp;
  }

  // ---- epilogue: publish partials ----
  gacc += __shfl_down(gacc, 2, 64);
  gacc += __shfl_down(gacc, 1, 64);
  if (q == 0) ws[bid * C_ + gc] = gacc;  // 256 G partials per block

  float sp = wave_reduce_sum(s_part);
  if (lane == 0) red_s[wv] = sp;  // red_s reuse: prologue long done
  __syncthreads();
  if (tid == 0) {
    float ssum = 0.f;
#pragma unroll
    for (int i = 0; i < 16; ++i) ssum += red_s[i];
    ws[SOFF + bid] = ssum;  // S partial
  }
}

// ---------------- Kernel 2: combine quarter partials -> g_out -------------
// 32768 outputs = 32 blocks x 1024 threads; one (nf, c) each.
__global__ __launch_bounds__(1024) void combine_kernel(
    float* __restrict__ out, const float* __restrict__ ws) {
  const int tg = blockIdx.x * 1024 + threadIdx.x;
  const int nf = tg >> 8, c = tg & 255;
  const int n = nf >> 4, f = nf & 15;
  const int b0 = nf << 2;
  const float G = ws[(b0 + 0) * C_ + c] + ws[(b0 + 1) * C_ + c] +
                  ws[(b0 + 2) * C_ + c] + ws[(b0 + 3) * C_ + c];
  const float S = ws[SOFF + b0] + ws[SOFF + b0 + 1] +
                  ws[SOFF + b0 + 2] + ws[SOFF + b0 + 3];
  out[COUT_SZ + (size_t)(n * C_ + c) * F_ + f] = G / S;
}

extern "C" void kernel_launch(void* const* d_in, const int* in_sizes, int n_in,
                              void* d_out, int out_size, void* d_ws,
                              size_t ws_size, hipStream_t stream) {
  const float* l = (const float*)d_in[0];
  const float* g = (const float*)d_in[1];
  const float* w = (const float*)d_in[2];
  float* out = (float*)d_out;
  float* ws = (float*)d_ws;  // [0,131072): G partials; [131072,131584): S
  fused_kernel<<<dim3(4 * N_ * F_), dim3(1024), 0, stream>>>(l, g, w, out, ws);
  combine_kernel<<<dim3(32), dim3(1024), 0, stream>>>(out, ws);
}

// Round 8
// 158.110 us; speedup vs baseline: 1.1342x; 1.0094x over previous
//
#include <hip/hip_runtime.h>
#include <math.h>

// Problem constants (fixed by setup_inputs)
constexpr int N_ = 8, C_ = 256, F_ = 16, WH_ = 784;
constexpr int CH_STRIDE = F_ * WH_;        // 12544 floats between channels
constexpr int COUT_SZ = N_ * F_ * WH_;     // 100352 floats (c output)
constexpr int QP = 392;                    // positions per block (half row)
constexpr int TILE = 56;                   // positions per LDS tile
constexpr int NT = 7;                      // tiles per block (7*56 = 392)
constexpr int F4PT = TILE / 4;             // 14 float4 per channel per tile
constexpr int TILE_F = C_ * TILE;          // 14336 floats per buffer (57.3 KB)
constexpr int SOFF = 256 * C_;             // ws offset of S partials

__device__ inline float wave_reduce_sum(float v) {
#pragma unroll
  for (int o = 32; o > 0; o >>= 1) v += __shfl_down(v, o, 64);
  return v;
}

// Async global->LDS, 16B per lane. LDS dest = wave-uniform base + lane*16
// (m104): LDS layout is linear float4 order; per-lane GLOBAL address carries
// the gather. Tracked by vmcnt; __syncthreads drains.
__device__ inline void gload16(const float* gp, float* lp) {
  __builtin_amdgcn_global_load_lds(
      (const __attribute__((address_space(1))) void*)gp,
      (__attribute__((address_space(3))) void*)lp, 16, 0, 0);
}

// ---------------- Kernel 1: fused single-read, 2-phase async pipeline ------
// R7 post-mortem: async pipeline was neutral at TILE=28 -> latency was never
// the limit; the limit is HBM request fragmentation (112-B segments per
// channel at 50-KB stride delivered ~3.1 TB/s). This round: TILE=56 doubles
// the per-channel contiguous segment to 224 B. Cost: 2x57.3 KB double buffer
// = 114.7 KB dynamic LDS -> 1 block/CU (grid 256 = (nf,half), QP=392=7x56).
// At 1 block/CU the async dbuf is what keeps HBM at full duty: tile t+1's
// gload_lds burst is in flight across ALL of tile t's compute; the final
// __syncthreads waits for it, but the memory pipe never idles.
// Max-free online softmax (proven R2-R7): S += sum exp(c), G_c += sum e*l;
// g_out = G/S combined across the two halves by K2.
__global__ __launch_bounds__(1024, 4) void fused_kernel(
    const float* __restrict__ l, const float* __restrict__ g,
    const float* __restrict__ w, float* __restrict__ out,
    float* __restrict__ ws) {
  extern __shared__ float dbuf[];  // 2 * TILE_F floats (114688 B)
  __shared__ float w_s[C_];
  __shared__ float e_s[TILE];
  __shared__ float red_s[16];
  __shared__ float gb_s;

  const int bid = blockIdx.x;
  const int nf = bid >> 1, half = bid & 1;
  const int n = nf >> 4, f = nf & 15;
  const int tid = threadIdx.x;
  const int lane = tid & 63, wv = tid >> 6;

  // ---- stage mapping: float4 idx within tile = c*14 + j ----
  // chunk k covers idx = k*1024 + tid; k=0..2 all threads, k=3 tid<512.
  // LDS float4-slot == idx (linear), uniform wave base = k*4096 + wv*256.
  int og[4];
#pragma unroll
  for (int k = 0; k < 4; ++k) {
    const int idx = k * 1024 + tid;
    const int c = idx / F4PT, j = idx - c * F4PT;
    og[k] = c * CH_STRIDE + (j << 2);  // per-lane float offset into l
  }
  const bool a3 = (wv < 8);  // chunk 3 active for waves 0..7 (tid<512)
  const size_t gbase =
      (size_t)n * (C_ * CH_STRIDE) + (size_t)f * WH_ + half * QP;

  float* cur = dbuf;
  float* nxt = dbuf + TILE_F;

  // issue tile 0 into cur; latency hides under the prologue
  {
    const float* lp = l + gbase;
    gload16(lp + og[0], &cur[wv << 8]);
    gload16(lp + og[1], &cur[4096 + (wv << 8)]);
    gload16(lp + og[2], &cur[8192 + (wv << 8)]);
    if (a3) gload16(lp + og[3], &cur[12288 + (wv << 8)]);
  }

  // ---- prologue: w into LDS, gb = sum_c g[n,c]*w[c] ----
  if (tid < C_) w_s[tid] = w[tid];
  float gv = (tid < C_) ? g[n * C_ + tid] * w[tid] : 0.f;
  gv = wave_reduce_sum(gv);
  if (lane == 0) red_s[wv] = gv;
  __syncthreads();  // drains vmcnt: tile 0 resident, w_s visible
  if (tid == 0) {
    float s = 0.f;
#pragma unroll
    for (int i = 0; i < 16; ++i) s += red_s[i];
    gb_s = s;
  }
  __syncthreads();
  const float gb = gb_s;

  // phase mappings
  const int p16 = tid >> 4, s16 = tid & 15;  // c-phase: 56 pos x 16 slices
  const int gc = tid >> 2, q = tid & 3;      // G-phase: 256 ch x 4 quarters

  float gacc = 0.f;    // G partial: channel gc, positions q*14..q*14+13
  float s_part = 0.f;  // S partial (s16==0 threads)

  for (int t = 0; t < NT; ++t) {
    // issue tile t+1 into nxt: in flight across BOTH compute phases
    if (t + 1 < NT) {
      const float* lp = l + gbase + (t + 1) * TILE;
      gload16(lp + og[0], &nxt[wv << 8]);
      gload16(lp + og[1], &nxt[4096 + (wv << 8)]);
      gload16(lp + og[2], &nxt[8192 + (wv << 8)]);
      if (a3) gload16(lp + og[3], &nxt[12288 + (wv << 8)]);
    }

    // ---- c-phase: c_p = sum_c l*w + gb; 16 lanes per position ----
    if (tid < TILE * 16) {  // 896 threads, waves 0..13
      float acc = 0.f;
#pragma unroll
      for (int k = 0; k < 16; ++k) {
        const int c = s16 + (k << 4);
        acc = fmaf(cur[c * TILE + p16], w_s[c], acc);
      }
      acc += __shfl_down(acc, 8, 64);
      acc += __shfl_down(acc, 4, 64);
      acc += __shfl_down(acc, 2, 64);
      acc += __shfl_down(acc, 1, 64);
      if (s16 == 0) {
        const float cp = acc + gb;
        out[nf * WH_ + half * QP + t * TILE + p16] = cp;
        const float e = __expf(cp);
        e_s[p16] = e;
        s_part += e;
      }
    }
    // e_s dependency is LDS-only: wait lgkm, NOT vmcnt (prefetch stays in
    // flight). m201-verified pattern; sched_barrier fences hoisting (#18).
    asm volatile("s_waitcnt lgkmcnt(0)" ::: "memory");
    __builtin_amdgcn_s_barrier();
    __builtin_amdgcn_sched_barrier(0);

    // ---- G-phase: thread (gc,q) accumulates 14 positions of channel gc ----
    {
      const int pb = q * F4PT;
#pragma unroll
      for (int j = 0; j < 14; ++j)
        gacc = fmaf(cur[gc * TILE + pb + j], e_s[pb + j], gacc);
    }
    __syncthreads();  // all cur/e_s reads done AND tile t+1 resident

    float* tmp = cur; cur = nxt; nxt = tmp;
  }

  // ---- epilogue: publish partials ----
  gacc += __shfl_down(gacc, 2, 64);
  gacc += __shfl_down(gacc, 1, 64);
  if (q == 0) ws[bid * C_ + gc] = gacc;  // 256 G partials per block

  float sp = wave_reduce_sum(s_part);
  if (lane == 0) red_s[wv] = sp;  // red_s reuse: prologue long done
  __syncthreads();
  if (tid == 0) {
    float ssum = 0.f;
#pragma unroll
    for (int i = 0; i < 16; ++i) ssum += red_s[i];
    ws[SOFF + bid] = ssum;  // S partial
  }
}

// ---------------- Kernel 2: combine half partials -> g_out ----------------
// 32768 outputs = 32 blocks x 1024 threads; one (nf, c) each.
__global__ __launch_bounds__(1024) void combine_kernel(
    float* __restrict__ out, const float* __restrict__ ws) {
  const int tg = blockIdx.x * 1024 + threadIdx.x;
  const int nf = tg >> 8, c = tg & 255;
  const int n = nf >> 4, f = nf & 15;
  const int b0 = nf << 1;
  const float G = ws[(b0 + 0) * C_ + c] + ws[(b0 + 1) * C_ + c];
  const float S = ws[SOFF + b0] + ws[SOFF + b0 + 1];
  out[COUT_SZ + (size_t)(n * C_ + c) * F_ + f] = G / S;
}

extern "C" void kernel_launch(void* const* d_in, const int* in_sizes, int n_in,
                              void* d_out, int out_size, void* d_ws,
                              size_t ws_size, hipStream_t stream) {
  const float* l = (const float*)d_in[0];
  const float* g = (const float*)d_in[1];
  const float* w = (const float*)d_in[2];
  float* out = (float*)d_out;
  float* ws = (float*)d_ws;  // [0,65536): G partials; [65536,65792): S
  fused_kernel<<<dim3(2 * N_ * F_), dim3(1024), 2 * TILE_F * sizeof(float),
                 stream>>>(l, g, w, out, ws);
  combine_kernel<<<dim3(32), dim3(1024), 0, stream>>>(out, ws);
}